// Round 8
// baseline (280.339 us; speedup 1.0000x reference)
//
#include <hip/hip_runtime.h>
#include <hip/hip_bf16.h>

#define N_NODES 50000
#define N_EDGES 800000
#define D 128
#define KCHEB 3
#define NBKT 98                        // buckets per k: node range 512
#define TOTB (KCHEB * NBKT)            // 294
#define SLAB 16384                     // slab capacity per bucket; expected ~8163
#define EPB 2048
#define NBLK_E ((N_EDGES + EPB - 1) / EPB)   // 391

typedef __attribute__((ext_vector_type(8))) short short8v;   // 8 bf16 (4 VGPRs)
typedef __attribute__((ext_vector_type(4))) float f32x4;

__device__ inline unsigned f2bf(float f) {   // fp32 -> bf16 bits, round-nearest-even
    unsigned x = __float_as_uint(f);
    unsigned r = ((x >> 16) & 1u) + 0x7FFFu;
    return (x + r) >> 16;
}

// ---------------- W prep: fp32 [k][kidx][n] -> bf16 transposed+swizzled [k][n][kidx] ----------------
__global__ __launch_bounds__(256) void wprep(const float* __restrict__ W,
                                             unsigned short* __restrict__ Wtg) {
    const int k = blockIdx.x;
    const float* Wk = W + (size_t)k * D * D;
    unsigned short* o = Wtg + (size_t)k * D * D;
    for (int i = threadIdx.x; i < 4096; i += 256) {   // float4 units
        int r  = i >> 5;                              // kidx
        int c4 = (i & 31) * 4;                        // n base
        float4 wv = *(const float4*)&Wk[r * 128 + c4];
        #pragma unroll
        for (int j = 0; j < 4; ++j) {
            int row = c4 + j;                         // n
            int byte_in_row = (r * 2) ^ ((row & 7) << 4);
            o[row * 128 + (byte_in_row >> 1)] = (unsigned short)f2bf((&wv.x)[j]);
        }
    }
}

// ---------------- MFMA GEMM: all 3 k per block; x read ONCE, kept in registers ----------------
__global__ __launch_bounds__(256) void gemm_mfma(const float* __restrict__ x,
                                                 const unsigned short* __restrict__ Wtg,
                                                 unsigned* __restrict__ h3, int n) {
    __shared__ unsigned short Wt[128 * 128];          // 32 KB, [n][kidx] swizzled
    const int t = threadIdx.x;
    const int lane = t & 63, w = t >> 6;
    const int m0 = blockIdx.x * 64 + w * 16;
    const int arow = m0 + (lane & 15);
    const float* xr = x + (size_t)(arow < n ? arow : 0) * D + ((lane >> 4) << 3);

    short8v afr[4];                                   // A-fragments, reused for all k
    #pragma unroll
    for (int kt = 0; kt < 4; ++kt) {
        float4 p0 = *(const float4*)(xr + kt * 32);
        float4 p1 = *(const float4*)(xr + kt * 32 + 4);
        union { short8v s; unsigned u[4]; } a;
        a.u[0] = f2bf(p0.x) | (f2bf(p0.y) << 16);
        a.u[1] = f2bf(p0.z) | (f2bf(p0.w) << 16);
        a.u[2] = f2bf(p1.x) | (f2bf(p1.y) << 16);
        a.u[3] = f2bf(p1.z) | (f2bf(p1.w) << 16);
        afr[kt] = a.s;
    }

    const int kb = (lane >> 4) << 4;
    const int orow_base = m0 + ((lane >> 4) << 2);
    const int col_base = lane & 15;

    for (int kc = 0; kc < KCHEB; ++kc) {
        __syncthreads();                              // previous iter's Wt reads done
        {
            const uint4* src = (const uint4*)(Wtg + (size_t)kc * D * D);
            uint4* dst = (uint4*)Wt;
            #pragma unroll
            for (int i = 0; i < 8; ++i) dst[t + 256 * i] = src[t + 256 * i];
        }
        __syncthreads();

        f32x4 acc[8] = {};
        #pragma unroll
        for (int nn = 0; nn < 8; ++nn) {
            const int row = nn * 16 + (lane & 15);
            const int sw = (row & 7) << 4;
            const unsigned short* wr = &Wt[row * 128];
            #pragma unroll
            for (int kt = 0; kt < 4; ++kt) {
                int byte_in_row = ((kt << 6) + kb) ^ sw;
                short8v b = *(const short8v*)&wr[byte_in_row >> 1];
                acc[nn] = __builtin_amdgcn_mfma_f32_16x16x32_bf16(afr[kt], b, acc[nn], 0, 0, 0);
            }
        }

        unsigned short* hs = (unsigned short*)(h3 + (size_t)kc * N_NODES * 64);
        #pragma unroll
        for (int nn = 0; nn < 8; ++nn) {
            int col = nn * 16 + col_base;
            #pragma unroll
            for (int r = 0; r < 4; ++r) {
                int orow = orow_base + r;
                if (orow < n) hs[(size_t)orow * D + col] = (unsigned short)f2bf(acc[nn][r]);
            }
        }
    }
}

// ---------------- bin edges by (k, dst>>9); meta u32 + w bf16 (6 B/edge) ----------------
__global__ __launch_bounds__(256) void bucket_bin(const int* __restrict__ ei,
                                                  const float* __restrict__ ew,
                                                  int* __restrict__ cursor,
                                                  unsigned* __restrict__ bmeta,
                                                  unsigned short* __restrict__ bw) {
    __shared__ int lh[NBKT], gb[NBKT], lc[NBKT];
    const int k = blockIdx.y, t = threadIdx.x;
    for (int i = t; i < NBKT; i += 256) { lh[i] = 0; lc[i] = 0; }
    __syncthreads();
    const int* srcs = ei + (size_t)k * 2 * N_EDGES;
    const int* dsts = srcs + N_EDGES;
    const float* w = ew + (size_t)k * N_EDGES;
    const int base = blockIdx.x * EPB;
    #pragma unroll
    for (int q = 0; q < EPB / 1024; ++q) {
        int e = base + q * 1024 + t * 4;
        if (e < N_EDGES) {
            int4 d4 = *(const int4*)&dsts[e];
            atomicAdd(&lh[d4.x >> 9], 1);
            atomicAdd(&lh[d4.y >> 9], 1);
            atomicAdd(&lh[d4.z >> 9], 1);
            atomicAdd(&lh[d4.w >> 9], 1);
        }
    }
    __syncthreads();
    for (int i = t; i < NBKT; i += 256)
        gb[i] = lh[i] ? atomicAdd(&cursor[k * NBKT + i], lh[i]) : 0;   // slab-local base
    __syncthreads();
    #pragma unroll
    for (int q = 0; q < EPB / 1024; ++q) {
        int e = base + q * 1024 + t * 4;
        if (e < N_EDGES) {
            int4 d4 = *(const int4*)&dsts[e];
            int4 s4 = *(const int4*)&srcs[e];
            float4 w4 = *(const float4*)&w[e];
            #pragma unroll
            for (int j = 0; j < 4; ++j) {
                int d = (&d4.x)[j];
                int b = d >> 9;
                int pos = (k * NBKT + b) * SLAB + gb[b] + atomicAdd(&lc[b], 1);
                bmeta[pos] = (unsigned)(&s4.x)[j] | ((unsigned)(d & 511) << 16);
                bw[pos] = (unsigned short)f2bf((&w4.x)[j]);
            }
        }
    }
}

// ---------------- per-bucket CSR build; csr entry = {src:u16 | w_bf16<<16} ----------------
__global__ __launch_bounds__(256) void build_csr(const unsigned* __restrict__ bmeta,
                                                 const unsigned short* __restrict__ bw,
                                                 const int* __restrict__ cursor,
                                                 int* __restrict__ off,
                                                 int* __restrict__ num,
                                                 unsigned* __restrict__ csr4) {
    __shared__ int nh[512], ex[512], wsum[4];
    const int kb = blockIdx.x;
    const int k = kb / NBKT, b = kb % NBKT;
    const int t = threadIdx.x;
    const int beg = kb * SLAB;
    const int end = beg + cursor[kb];

    for (int i = t; i < 512; i += 256) nh[i] = 0;
    __syncthreads();
    for (int i = beg + t; i < end; i += 256)
        atomicAdd(&nh[(bmeta[i] >> 16) & 511], 1);
    __syncthreads();

    int a0 = nh[2 * t], a1 = nh[2 * t + 1];
    int s = a0 + a1;
    int lane = t & 63, wid = t >> 6;
    int v = s;
    #pragma unroll
    for (int d = 1; d < 64; d <<= 1) {
        int u = __shfl_up(v, d, 64);
        if (lane >= d) v += u;
    }
    if (lane == 63) wsum[wid] = v;
    __syncthreads();
    int wb = 0;
    for (int i = 0; i < wid; ++i) wb += wsum[i];
    int ep = wb + v - s;
    ex[2 * t] = ep;
    ex[2 * t + 1] = ep + a0;

    const int node0 = b * 512;
    int n0 = node0 + 2 * t, n1 = node0 + 2 * t + 1;
    if (n0 < N_NODES) { off[k * N_NODES + n0] = beg + ep;      num[k * N_NODES + n0] = a0; }
    if (n1 < N_NODES) { off[k * N_NODES + n1] = beg + ep + a0; num[k * N_NODES + n1] = a1; }

    for (int i = t; i < 512; i += 256) nh[i] = 0;   // reuse as cursor
    __syncthreads();
    for (int i = beg + t; i < end; i += 256) {
        unsigned m = bmeta[i];
        int dl = (m >> 16) & 511;
        int pos = beg + ex[dl] + atomicAdd(&nh[dl], 1);
        csr4[pos] = (m & 0xFFFFu) | ((unsigned)bw[i] << 16);
    }
}

// ---------------- merged gather: one node per 16-lane quarter-wave, uint4 h loads ----------------
__global__ __launch_bounds__(256) void gather_all(const unsigned* __restrict__ h3,
                                                  const unsigned* __restrict__ csr4,
                                                  const int* __restrict__ off,
                                                  const int* __restrict__ num,
                                                  float* __restrict__ out) {
    const int q = threadIdx.x >> 4;                  // 0..15
    const int l = threadIdx.x & 15;
    const int node = blockIdx.x * 16 + q;
    if (node >= N_NODES) return;

    float a0 = 0.f, a1 = 0.f, a2 = 0.f, a3 = 0.f;
    float a4 = 0.f, a5 = 0.f, a6 = 0.f, a7 = 0.f;
    #pragma unroll
    for (int k = 0; k < KCHEB; ++k) {
        const unsigned* h2 = h3 + (size_t)k * N_NODES * 64;
        const int kd = k * N_NODES + node;
        int i = off[kd];
        const int end = i + num[kd];
        for (; i + 8 <= end; i += 8) {
            unsigned e[8];
            uint4 u[8];
            #pragma unroll
            for (int j = 0; j < 8; ++j) e[j] = csr4[i + j];
            #pragma unroll
            for (int j = 0; j < 8; ++j)
                u[j] = *(const uint4*)&h2[(size_t)(e[j] & 0xFFFFu) * 64 + l * 4];
            #pragma unroll
            for (int j = 0; j < 8; ++j) {
                float w = __uint_as_float(e[j] & 0xFFFF0000u);
                a0 += w * __uint_as_float(u[j].x << 16);
                a1 += w * __uint_as_float(u[j].x & 0xFFFF0000u);
                a2 += w * __uint_as_float(u[j].y << 16);
                a3 += w * __uint_as_float(u[j].y & 0xFFFF0000u);
                a4 += w * __uint_as_float(u[j].z << 16);
                a5 += w * __uint_as_float(u[j].z & 0xFFFF0000u);
                a6 += w * __uint_as_float(u[j].w << 16);
                a7 += w * __uint_as_float(u[j].w & 0xFFFF0000u);
            }
        }
        for (; i < end; ++i) {
            unsigned e = csr4[i];
            float w = __uint_as_float(e & 0xFFFF0000u);
            uint4 u = *(const uint4*)&h2[(size_t)(e & 0xFFFFu) * 64 + l * 4];
            a0 += w * __uint_as_float(u.x << 16);
            a1 += w * __uint_as_float(u.x & 0xFFFF0000u);
            a2 += w * __uint_as_float(u.y << 16);
            a3 += w * __uint_as_float(u.y & 0xFFFF0000u);
            a4 += w * __uint_as_float(u.z << 16);
            a5 += w * __uint_as_float(u.z & 0xFFFF0000u);
            a6 += w * __uint_as_float(u.w << 16);
            a7 += w * __uint_as_float(u.w & 0xFFFF0000u);
        }
    }
    float* op = &out[(size_t)node * D + l * 8];
    *(float4*)(op)     = make_float4(a0, a1, a2, a3);
    *(float4*)(op + 4) = make_float4(a4, a5, a6, a7);
}

extern "C" void kernel_launch(void* const* d_in, const int* in_sizes, int n_in,
                              void* d_out, int out_size, void* d_ws, size_t ws_size,
                              hipStream_t stream) {
    const float* x  = (const float*)d_in[0];
    const float* W  = (const float*)d_in[1];
    const int*   ei = (const int*)d_in[2];
    const float* ew = (const float*)d_in[3];
    float* out = (float*)d_out;

    // workspace layout (bytes) — ws_size = 256 MiB
    char* ws = (char*)d_ws;
    unsigned*       csr4   = (unsigned*)      (ws);                // 19,267,584
    unsigned*       bmeta  = (unsigned*)      (ws + 19267584);     // 19,267,584
    unsigned short* bw     = (unsigned short*)(ws + 38535168);     //  9,633,792
    unsigned*       h3     = (unsigned*)      (ws + 48168960);     // 38,400,000
    int*            off    = (int*)           (ws + 86568960);     //    600,000
    int*            num    = (int*)           (ws + 87168960);     //    600,000
    int*            cursor = (int*)           (ws + 87768960);     //      1,176
    unsigned short* Wtg    = (unsigned short*)(ws + 87770136);     //     98,304

    hipMemsetAsync(cursor, 0, TOTB * sizeof(int), stream);

    wprep<<<KCHEB, 256, 0, stream>>>(W, Wtg);

    const dim3 egrid(NBLK_E, KCHEB);                        // (391, 3)
    bucket_bin<<<egrid, 256, 0, stream>>>(ei, ew, cursor, bmeta, bw);

    gemm_mfma<<<(N_NODES + 63) / 64, 256, 0, stream>>>(x, Wtg, h3, N_NODES);

    build_csr<<<TOTB, 256, 0, stream>>>(bmeta, bw, cursor, off, num, csr4);

    const int gat_grid = (N_NODES + 15) / 16;               // 3125
    gather_all<<<gat_grid, 256, 0, stream>>>(h3, csr4, off, num, out);
}

// Round 9
// 252.523 us; speedup vs baseline: 1.1102x; 1.1102x over previous
//
#include <hip/hip_runtime.h>
#include <hip/hip_bf16.h>

#define N_NODES 50000
#define N_EDGES 800000
#define D 128
#define KCHEB 3
#define NBKT 98                        // buckets per k: node range 512
#define TOTB (KCHEB * NBKT)            // 294
#define SLAB 16384                     // slab capacity per bucket; expected ~8163
#define EPB 4096
#define NBLK_E ((N_EDGES + EPB - 1) / EPB)   // 196

typedef __attribute__((ext_vector_type(8))) short short8v;   // 8 bf16 (4 VGPRs)
typedef __attribute__((ext_vector_type(4))) float f32x4;

__device__ inline unsigned f2bf(float f) {   // fp32 -> bf16 bits, round-nearest-even
    unsigned x = __float_as_uint(f);
    unsigned r = ((x >> 16) & 1u) + 0x7FFFu;
    return (x + r) >> 16;
}

// ---------------- W prep: fp32 [k][kidx][n] -> bf16 transposed+swizzled [k][n][kidx] ----------------
__global__ __launch_bounds__(256) void wprep(const float* __restrict__ W,
                                             unsigned short* __restrict__ Wtg) {
    const int k = blockIdx.x;
    const float* Wk = W + (size_t)k * D * D;
    unsigned short* o = Wtg + (size_t)k * D * D;
    for (int i = threadIdx.x; i < 4096; i += 256) {   // float4 units
        int r  = i >> 5;                              // kidx
        int c4 = (i & 31) * 4;                        // n base
        float4 wv = *(const float4*)&Wk[r * 128 + c4];
        #pragma unroll
        for (int j = 0; j < 4; ++j) {
            int row = c4 + j;                         // n
            int byte_in_row = (r * 2) ^ ((row & 7) << 4);
            o[row * 128 + (byte_in_row >> 1)] = (unsigned short)f2bf((&wv.x)[j]);
        }
    }
}

// ---------------- MFMA GEMM: h_bf16[k] = x @ W_k  (gridDim.y = k) ----------------
__global__ __launch_bounds__(256) void gemm_mfma(const float* __restrict__ x,
                                                 const unsigned short* __restrict__ Wtg,
                                                 unsigned* __restrict__ h3, int n) {
    __shared__ unsigned short Wt[128 * 128];          // 32 KB, [n][kidx] swizzled
    const int t = threadIdx.x;
    unsigned* h2 = h3 + (size_t)blockIdx.y * N_NODES * 64;

    {   // pure 32 KB copy, already converted/transposed/swizzled
        const uint4* src = (const uint4*)(Wtg + (size_t)blockIdx.y * D * D);
        uint4* dst = (uint4*)Wt;
        #pragma unroll
        for (int i = 0; i < 8; ++i) dst[t + 256 * i] = src[t + 256 * i];
    }
    __syncthreads();

    const int lane = t & 63, w = t >> 6;
    const int m0 = blockIdx.x * 64 + w * 16;
    const int arow = m0 + (lane & 15);
    const float* xr = x + (size_t)(arow < n ? arow : 0) * D + ((lane >> 4) << 3);

    short8v afr[4];
    #pragma unroll
    for (int kt = 0; kt < 4; ++kt) {
        float4 p0 = *(const float4*)(xr + kt * 32);
        float4 p1 = *(const float4*)(xr + kt * 32 + 4);
        union { short8v s; unsigned u[4]; } a;
        a.u[0] = f2bf(p0.x) | (f2bf(p0.y) << 16);
        a.u[1] = f2bf(p0.z) | (f2bf(p0.w) << 16);
        a.u[2] = f2bf(p1.x) | (f2bf(p1.y) << 16);
        a.u[3] = f2bf(p1.z) | (f2bf(p1.w) << 16);
        afr[kt] = a.s;
    }

    f32x4 acc[8] = {};
    const int kb = (lane >> 4) << 4;
    #pragma unroll
    for (int nn = 0; nn < 8; ++nn) {
        const int row = nn * 16 + (lane & 15);
        const int sw = (row & 7) << 4;
        const unsigned short* wr = &Wt[row * 128];
        #pragma unroll
        for (int kt = 0; kt < 4; ++kt) {
            int byte_in_row = ((kt << 6) + kb) ^ sw;
            short8v b = *(const short8v*)&wr[byte_in_row >> 1];
            acc[nn] = __builtin_amdgcn_mfma_f32_16x16x32_bf16(afr[kt], b, acc[nn], 0, 0, 0);
        }
    }

    unsigned short* hs = (unsigned short*)h2;
    const int orow_base = m0 + ((lane >> 4) << 2);
    const int col_base = lane & 15;
    #pragma unroll
    for (int nn = 0; nn < 8; ++nn) {
        int col = nn * 16 + col_base;
        #pragma unroll
        for (int r = 0; r < 4; ++r) {
            int orow = orow_base + r;
            if (orow < n) hs[(size_t)orow * D + col] = (unsigned short)f2bf(acc[nn][r]);
        }
    }
}

// ---------------- bin edges by (k, dst>>9) into fixed slabs (1024 threads) ----------------
__global__ __launch_bounds__(1024) void bucket_bin(const int* __restrict__ ei,
                                                   const float* __restrict__ ew,
                                                   int* __restrict__ cursor,
                                                   uint2* __restrict__ binned) {
    __shared__ int lh[NBKT], gb[NBKT], lc[NBKT];
    const int k = blockIdx.y, t = threadIdx.x;
    for (int i = t; i < NBKT; i += 1024) { lh[i] = 0; lc[i] = 0; }
    __syncthreads();
    const int* srcs = ei + (size_t)k * 2 * N_EDGES;
    const int* dsts = srcs + N_EDGES;
    const float* w = ew + (size_t)k * N_EDGES;
    const int e = blockIdx.x * EPB + t * 4;           // EPB = 4096 = 1024*4

    if (e < N_EDGES) {
        int4 d4 = *(const int4*)&dsts[e];
        atomicAdd(&lh[d4.x >> 9], 1);
        atomicAdd(&lh[d4.y >> 9], 1);
        atomicAdd(&lh[d4.z >> 9], 1);
        atomicAdd(&lh[d4.w >> 9], 1);
    }
    __syncthreads();
    for (int i = t; i < NBKT; i += 1024)
        gb[i] = lh[i] ? atomicAdd(&cursor[k * NBKT + i], lh[i]) : 0;   // slab-local base
    __syncthreads();
    if (e < N_EDGES) {
        int4 d4 = *(const int4*)&dsts[e];
        int4 s4 = *(const int4*)&srcs[e];
        float4 w4 = *(const float4*)&w[e];
        #pragma unroll
        for (int j = 0; j < 4; ++j) {
            int d = (&d4.x)[j];
            int b = d >> 9;
            int pos = (k * NBKT + b) * SLAB + gb[b] + atomicAdd(&lc[b], 1);
            binned[pos] = make_uint2(__float_as_uint((&w4.x)[j]),
                                     (unsigned)(&s4.x)[j] | ((unsigned)(d & 511) << 16));
        }
    }
}

// ---------------- per-bucket CSR build (1024 threads); csr = {src:u16 | w_bf16<<16} ----------------
__global__ __launch_bounds__(1024) void build_csr(const uint2* __restrict__ binned,
                                                  const int* __restrict__ cursor,
                                                  int* __restrict__ off,
                                                  int* __restrict__ num,
                                                  unsigned* __restrict__ csr4) {
    __shared__ int nh[512], ex[512], wsum[4];
    const int kb = blockIdx.x;
    const int k = kb / NBKT, b = kb % NBKT;
    const int t = threadIdx.x;
    const int beg = kb * SLAB;
    const int end = beg + cursor[kb];

    for (int i = t; i < 512; i += 1024) nh[i] = 0;
    __syncthreads();
    for (int i = beg + t; i < end; i += 1024)
        atomicAdd(&nh[(binned[i].y >> 16) & 511], 1);
    __syncthreads();

    if (t < 256) {                                    // scan by first 4 waves
        int a0 = nh[2 * t], a1 = nh[2 * t + 1];
        int s = a0 + a1;
        int lane = t & 63, wid = t >> 6;
        int v = s;
        #pragma unroll
        for (int d = 1; d < 64; d <<= 1) {
            int u = __shfl_up(v, d, 64);
            if (lane >= d) v += u;
        }
        if (lane == 63) wsum[wid] = v;
        __syncthreads();
        int wb = 0;
        for (int i = 0; i < wid; ++i) wb += wsum[i];
        int ep = wb + v - s;
        ex[2 * t] = ep;
        ex[2 * t + 1] = ep + a0;

        const int node0 = b * 512;
        int n0 = node0 + 2 * t, n1 = node0 + 2 * t + 1;
        if (n0 < N_NODES) { off[k * N_NODES + n0] = beg + ep;      num[k * N_NODES + n0] = a0; }
        if (n1 < N_NODES) { off[k * N_NODES + n1] = beg + ep + a0; num[k * N_NODES + n1] = a1; }
    } else {
        __syncthreads();                              // match the scan's barrier
    }
    for (int i = t; i < 512; i += 1024) nh[i] = 0;    // reuse as cursor
    __syncthreads();
    for (int i = beg + t; i < end; i += 1024) {
        uint2 e = binned[i];
        int dl = (e.y >> 16) & 511;
        int pos = beg + ex[dl] + atomicAdd(&nh[dl], 1);
        csr4[pos] = (e.y & 0xFFFFu) | (f2bf(__uint_as_float(e.x)) << 16);
    }
}

// ---------------- merged gather: one node per 32-lane half-wave, all 3 k's ----------------
__global__ __launch_bounds__(256) void gather_all(const unsigned* __restrict__ h3,
                                                  const unsigned* __restrict__ csr4,
                                                  const int* __restrict__ off,
                                                  const int* __restrict__ num,
                                                  float* __restrict__ out) {
    const int half = threadIdx.x >> 5;               // 0..7
    const int l = threadIdx.x & 31;
    const int node = blockIdx.x * 8 + half;
    if (node >= N_NODES) return;

    float a0 = 0.f, a1 = 0.f, a2 = 0.f, a3 = 0.f;
    #pragma unroll
    for (int k = 0; k < KCHEB; ++k) {
        const unsigned* h2 = h3 + (size_t)k * N_NODES * 64;
        const int kd = k * N_NODES + node;
        int i = off[kd];
        const int end = i + num[kd];
        for (; i + 8 <= end; i += 8) {
            unsigned e[8];
            uint2 u[8];
            #pragma unroll
            for (int j = 0; j < 8; ++j) e[j] = csr4[i + j];
            #pragma unroll
            for (int j = 0; j < 8; ++j)
                u[j] = *(const uint2*)&h2[(size_t)(e[j] & 0xFFFFu) * 64 + l * 2];
            #pragma unroll
            for (int j = 0; j < 8; ++j) {
                float w = __uint_as_float(e[j] & 0xFFFF0000u);
                a0 += w * __uint_as_float(u[j].x << 16);
                a1 += w * __uint_as_float(u[j].x & 0xFFFF0000u);
                a2 += w * __uint_as_float(u[j].y << 16);
                a3 += w * __uint_as_float(u[j].y & 0xFFFF0000u);
            }
        }
        for (; i < end; ++i) {
            unsigned e = csr4[i];
            float w = __uint_as_float(e & 0xFFFF0000u);
            uint2 u = *(const uint2*)&h2[(size_t)(e & 0xFFFFu) * 64 + l * 2];
            a0 += w * __uint_as_float(u.x << 16);
            a1 += w * __uint_as_float(u.x & 0xFFFF0000u);
            a2 += w * __uint_as_float(u.y << 16);
            a3 += w * __uint_as_float(u.y & 0xFFFF0000u);
        }
    }
    *(float4*)&out[(size_t)node * D + l * 4] = make_float4(a0, a1, a2, a3);
}

extern "C" void kernel_launch(void* const* d_in, const int* in_sizes, int n_in,
                              void* d_out, int out_size, void* d_ws, size_t ws_size,
                              hipStream_t stream) {
    const float* x  = (const float*)d_in[0];
    const float* W  = (const float*)d_in[1];
    const int*   ei = (const int*)d_in[2];
    const float* ew = (const float*)d_in[3];
    float* out = (float*)d_out;

    // workspace layout (bytes) — ws_size = 256 MiB
    char* ws = (char*)d_ws;
    unsigned*       csr4   = (unsigned*)      (ws);                // 19,267,584
    uint2*          binned = (uint2*)         (ws + 19267584);     // 38,535,168
    unsigned*       h3     = (unsigned*)      (ws + 57802752);     // 38,400,000
    int*            off    = (int*)           (ws + 96202752);     //    600,000
    int*            num    = (int*)           (ws + 96802752);     //    600,000
    int*            cursor = (int*)           (ws + 97402752);     //      1,176
    unsigned short* Wtg    = (unsigned short*)(ws + 97403936);     //     98,304

    hipMemsetAsync(cursor, 0, TOTB * sizeof(int), stream);

    wprep<<<KCHEB, 256, 0, stream>>>(W, Wtg);

    const dim3 egrid(NBLK_E, KCHEB);                        // (196, 3)
    bucket_bin<<<egrid, 1024, 0, stream>>>(ei, ew, cursor, binned);

    const dim3 ggrid((N_NODES + 63) / 64, KCHEB);           // (782, 3)
    gemm_mfma<<<ggrid, 256, 0, stream>>>(x, Wtg, h3, N_NODES);

    build_csr<<<TOTB, 1024, 0, stream>>>(binned, cursor, off, num, csr4);

    const int gat_grid = (N_NODES + 7) / 8;                 // 6250
    gather_all<<<gat_grid, 256, 0, stream>>>(h3, csr4, off, num, out);
}

// Round 10
// 250.961 us; speedup vs baseline: 1.1171x; 1.0062x over previous
//
#include <hip/hip_runtime.h>
#include <hip/hip_bf16.h>

#define N_NODES 50000
#define N_EDGES 800000
#define D 128
#define KCHEB 3
#define NBKT 98                        // buckets per k: node range 512
#define TOTB (KCHEB * NBKT)            // 294
#define SLAB 16384                     // slab capacity per bucket; expected ~8163
#define EPB 4096
#define NBLK_E ((N_EDGES + EPB - 1) / EPB)   // 196

typedef __attribute__((ext_vector_type(8))) short short8v;   // 8 bf16 (4 VGPRs)
typedef __attribute__((ext_vector_type(4))) float f32x4;

__device__ inline unsigned f2bf(float f) {   // fp32 -> bf16 bits, round-nearest-even
    unsigned x = __float_as_uint(f);
    unsigned r = ((x >> 16) & 1u) + 0x7FFFu;
    return (x + r) >> 16;
}

// ---------------- W prep: fp32 [k][kidx][n] -> bf16 transposed+swizzled [k][n][kidx];
// ---------------- block 0 also zeroes the bucket cursors (replaces memset dispatch) ----
__global__ __launch_bounds__(256) void wprep(const float* __restrict__ W,
                                             unsigned short* __restrict__ Wtg,
                                             int* __restrict__ cursor) {
    const int k = blockIdx.x;
    if (k == 0)
        for (int i = threadIdx.x; i < TOTB; i += 256) cursor[i] = 0;
    const float* Wk = W + (size_t)k * D * D;
    unsigned short* o = Wtg + (size_t)k * D * D;
    for (int i = threadIdx.x; i < 4096; i += 256) {   // float4 units
        int r  = i >> 5;                              // kidx
        int c4 = (i & 31) * 4;                        // n base
        float4 wv = *(const float4*)&Wk[r * 128 + c4];
        #pragma unroll
        for (int j = 0; j < 4; ++j) {
            int row = c4 + j;                         // n
            int byte_in_row = (r * 2) ^ ((row & 7) << 4);
            o[row * 128 + (byte_in_row >> 1)] = (unsigned short)f2bf((&wv.x)[j]);
        }
    }
}

// ---------------- MFMA GEMM: h_bf16[k] = x @ W_k  (gridDim.y = k) ----------------
// Operands SWAPPED: D = Wt_frag x x_frag -> D[n][node]; node = lane&15 (col),
// n = (lane>>4)*4 + reg (row) -> each thread packs 4 consecutive n's -> uint2 store.
__global__ __launch_bounds__(256) void gemm_mfma(const float* __restrict__ x,
                                                 const unsigned short* __restrict__ Wtg,
                                                 unsigned* __restrict__ h3, int n) {
    __shared__ unsigned short Wt[128 * 128];          // 32 KB, [n][kidx] swizzled
    const int t = threadIdx.x;
    unsigned* h2 = h3 + (size_t)blockIdx.y * N_NODES * 64;

    {   // pure 32 KB copy, already converted/transposed/swizzled
        const uint4* src = (const uint4*)(Wtg + (size_t)blockIdx.y * D * D);
        uint4* dst = (uint4*)Wt;
        #pragma unroll
        for (int i = 0; i < 8; ++i) dst[t + 256 * i] = src[t + 256 * i];
    }
    __syncthreads();

    const int lane = t & 63, w = t >> 6;
    const int m0 = blockIdx.x * 64 + w * 16;
    const int arow = m0 + (lane & 15);
    const float* xr = x + (size_t)(arow < n ? arow : 0) * D + ((lane >> 4) << 3);

    short8v afr[4];                                   // x fragment (B operand now)
    #pragma unroll
    for (int kt = 0; kt < 4; ++kt) {
        float4 p0 = *(const float4*)(xr + kt * 32);
        float4 p1 = *(const float4*)(xr + kt * 32 + 4);
        union { short8v s; unsigned u[4]; } a;
        a.u[0] = f2bf(p0.x) | (f2bf(p0.y) << 16);
        a.u[1] = f2bf(p0.z) | (f2bf(p0.w) << 16);
        a.u[2] = f2bf(p1.x) | (f2bf(p1.y) << 16);
        a.u[3] = f2bf(p1.z) | (f2bf(p1.w) << 16);
        afr[kt] = a.s;
    }

    f32x4 acc[8] = {};
    const int kb = (lane >> 4) << 4;
    #pragma unroll
    for (int nn = 0; nn < 8; ++nn) {
        const int row = nn * 16 + (lane & 15);        // Wt row (n index)
        const int sw = (row & 7) << 4;
        const unsigned short* wr = &Wt[row * 128];
        #pragma unroll
        for (int kt = 0; kt < 4; ++kt) {
            int byte_in_row = ((kt << 6) + kb) ^ sw;
            short8v b = *(const short8v*)&wr[byte_in_row >> 1];
            // SWAPPED: A = Wt fragment, B = x fragment
            acc[nn] = __builtin_amdgcn_mfma_f32_16x16x32_bf16(b, afr[kt], acc[nn], 0, 0, 0);
        }
    }

    // D[n][node]: col = lane&15 = node - m0, row = (lane>>4)*4 + r = n - nn*16
    const int node = m0 + (lane & 15);
    if (node < n) {
        unsigned short* hs = (unsigned short*)h2;
        const int g4 = (lane >> 4) << 2;
        #pragma unroll
        for (int nn = 0; nn < 8; ++nn) {
            unsigned lo = f2bf(acc[nn][0]) | (f2bf(acc[nn][1]) << 16);
            unsigned hi = f2bf(acc[nn][2]) | (f2bf(acc[nn][3]) << 16);
            *(uint2*)&hs[(size_t)node * D + nn * 16 + g4] = make_uint2(lo, hi);
        }
    }
}

// ---------------- bin edges by (k, dst>>9) into fixed slabs (1024 threads) ----------------
__global__ __launch_bounds__(1024) void bucket_bin(const int* __restrict__ ei,
                                                   const float* __restrict__ ew,
                                                   int* __restrict__ cursor,
                                                   uint2* __restrict__ binned) {
    __shared__ int lh[NBKT], gb[NBKT], lc[NBKT];
    const int k = blockIdx.y, t = threadIdx.x;
    for (int i = t; i < NBKT; i += 1024) { lh[i] = 0; lc[i] = 0; }
    __syncthreads();
    const int* srcs = ei + (size_t)k * 2 * N_EDGES;
    const int* dsts = srcs + N_EDGES;
    const float* w = ew + (size_t)k * N_EDGES;
    const int e = blockIdx.x * EPB + t * 4;           // EPB = 4096 = 1024*4
    const bool ok = e < N_EDGES;

    int4 d4 = make_int4(0, 0, 0, 0), s4 = make_int4(0, 0, 0, 0);
    float4 w4 = make_float4(0.f, 0.f, 0.f, 0.f);
    if (ok) {                                         // load ONCE, reuse in both passes
        d4 = *(const int4*)&dsts[e];
        s4 = *(const int4*)&srcs[e];
        w4 = *(const float4*)&w[e];
        atomicAdd(&lh[d4.x >> 9], 1);
        atomicAdd(&lh[d4.y >> 9], 1);
        atomicAdd(&lh[d4.z >> 9], 1);
        atomicAdd(&lh[d4.w >> 9], 1);
    }
    __syncthreads();
    for (int i = t; i < NBKT; i += 1024)
        gb[i] = lh[i] ? atomicAdd(&cursor[k * NBKT + i], lh[i]) : 0;   // slab-local base
    __syncthreads();
    if (ok) {
        #pragma unroll
        for (int j = 0; j < 4; ++j) {
            int d = (&d4.x)[j];
            int b = d >> 9;
            int pos = (k * NBKT + b) * SLAB + gb[b] + atomicAdd(&lc[b], 1);
            binned[pos] = make_uint2(__float_as_uint((&w4.x)[j]),
                                     (unsigned)(&s4.x)[j] | ((unsigned)(d & 511) << 16));
        }
    }
}

// ---------------- per-bucket CSR build (1024 threads); csr = {src:u16 | w_bf16<<16} ----------------
__global__ __launch_bounds__(1024) void build_csr(const uint2* __restrict__ binned,
                                                  const int* __restrict__ cursor,
                                                  int* __restrict__ off,
                                                  int* __restrict__ num,
                                                  unsigned* __restrict__ csr4) {
    __shared__ int nh[512], ex[512], wsum[4];
    const int kb = blockIdx.x;
    const int k = kb / NBKT, b = kb % NBKT;
    const int t = threadIdx.x;
    const int beg = kb * SLAB;
    const int end = beg + cursor[kb];

    for (int i = t; i < 512; i += 1024) nh[i] = 0;
    __syncthreads();
    for (int i = beg + t; i < end; i += 1024)
        atomicAdd(&nh[(binned[i].y >> 16) & 511], 1);
    __syncthreads();

    if (t < 256) {                                    // scan by first 4 waves
        int a0 = nh[2 * t], a1 = nh[2 * t + 1];
        int s = a0 + a1;
        int lane = t & 63, wid = t >> 6;
        int v = s;
        #pragma unroll
        for (int d = 1; d < 64; d <<= 1) {
            int u = __shfl_up(v, d, 64);
            if (lane >= d) v += u;
        }
        if (lane == 63) wsum[wid] = v;
        __syncthreads();
        int wb = 0;
        for (int i = 0; i < wid; ++i) wb += wsum[i];
        int ep = wb + v - s;
        ex[2 * t] = ep;
        ex[2 * t + 1] = ep + a0;

        const int node0 = b * 512;
        int n0 = node0 + 2 * t, n1 = node0 + 2 * t + 1;
        if (n0 < N_NODES) { off[k * N_NODES + n0] = beg + ep;      num[k * N_NODES + n0] = a0; }
        if (n1 < N_NODES) { off[k * N_NODES + n1] = beg + ep + a0; num[k * N_NODES + n1] = a1; }
    } else {
        __syncthreads();                              // match the scan's barrier
    }
    for (int i = t; i < 512; i += 1024) nh[i] = 0;    // reuse as cursor
    __syncthreads();
    for (int i = beg + t; i < end; i += 1024) {
        uint2 e = binned[i];
        int dl = (e.y >> 16) & 511;
        int pos = beg + ex[dl] + atomicAdd(&nh[dl], 1);
        csr4[pos] = (e.y & 0xFFFFu) | (f2bf(__uint_as_float(e.x)) << 16);
    }
}

// ---------------- merged gather: one node per 32-lane half-wave, predicated 8-batches ----------------
__global__ __launch_bounds__(256) void gather_all(const unsigned* __restrict__ h3,
                                                  const unsigned* __restrict__ csr4,
                                                  const int* __restrict__ off,
                                                  const int* __restrict__ num,
                                                  float* __restrict__ out) {
    const int half = threadIdx.x >> 5;               // 0..7
    const int l = threadIdx.x & 31;
    const int node = blockIdx.x * 8 + half;
    if (node >= N_NODES) return;

    float a0 = 0.f, a1 = 0.f, a2 = 0.f, a3 = 0.f;
    #pragma unroll
    for (int k = 0; k < KCHEB; ++k) {
        const unsigned* h2 = h3 + (size_t)k * N_NODES * 64;
        const int kd = k * N_NODES + node;
        const int i0 = off[kd];
        const int cnt = num[kd];
        for (int b0 = 0; b0 < cnt; b0 += 8) {
            unsigned e[8];
            uint2 u[8];
            float wv[8];
            #pragma unroll
            for (int j = 0; j < 8; ++j) {
                bool okj = (b0 + j) < cnt;
                e[j] = csr4[okj ? i0 + b0 + j : i0];
                wv[j] = okj ? __uint_as_float(e[j] & 0xFFFF0000u) : 0.f;
            }
            #pragma unroll
            for (int j = 0; j < 8; ++j)
                u[j] = *(const uint2*)&h2[(size_t)(e[j] & 0xFFFFu) * 64 + l * 2];
            #pragma unroll
            for (int j = 0; j < 8; ++j) {
                a0 += wv[j] * __uint_as_float(u[j].x << 16);
                a1 += wv[j] * __uint_as_float(u[j].x & 0xFFFF0000u);
                a2 += wv[j] * __uint_as_float(u[j].y << 16);
                a3 += wv[j] * __uint_as_float(u[j].y & 0xFFFF0000u);
            }
        }
    }
    *(float4*)&out[(size_t)node * D + l * 4] = make_float4(a0, a1, a2, a3);
}

extern "C" void kernel_launch(void* const* d_in, const int* in_sizes, int n_in,
                              void* d_out, int out_size, void* d_ws, size_t ws_size,
                              hipStream_t stream) {
    const float* x  = (const float*)d_in[0];
    const float* W  = (const float*)d_in[1];
    const int*   ei = (const int*)d_in[2];
    const float* ew = (const float*)d_in[3];
    float* out = (float*)d_out;

    // workspace layout (bytes) — ws_size = 256 MiB
    char* ws = (char*)d_ws;
    unsigned*       csr4   = (unsigned*)      (ws);                // 19,267,584
    uint2*          binned = (uint2*)         (ws + 19267584);     // 38,535,168
    unsigned*       h3     = (unsigned*)      (ws + 57802752);     // 38,400,000
    int*            off    = (int*)           (ws + 96202752);     //    600,000
    int*            num    = (int*)           (ws + 96802752);     //    600,000
    int*            cursor = (int*)           (ws + 97402752);     //      1,176
    unsigned short* Wtg    = (unsigned short*)(ws + 97403936);     //     98,304

    wprep<<<KCHEB, 256, 0, stream>>>(W, Wtg, cursor);

    const dim3 egrid(NBLK_E, KCHEB);                        // (196, 3)
    bucket_bin<<<egrid, 1024, 0, stream>>>(ei, ew, cursor, binned);

    const dim3 ggrid((N_NODES + 63) / 64, KCHEB);           // (782, 3)
    gemm_mfma<<<ggrid, 256, 0, stream>>>(x, Wtg, h3, N_NODES);

    build_csr<<<TOTB, 1024, 0, stream>>>(binned, cursor, off, num, csr4);

    const int gat_grid = (N_NODES + 7) / 8;                 // 6250
    gather_all<<<gat_grid, 256, 0, stream>>>(h3, csr4, off, num, out);
}